// Round 2
// baseline (2329.450 us; speedup 1.0000x reference)
//
#include <hip/hip_runtime.h>
#include <math.h>

#define BATCH 4
#define P 3072
#define NROW (BATCH * P)        // 12288
#define MAXIT 50
#define RPB 16                  // rows per block in LSE pass (one MFMA row-tile)
#define LSE_GRID (NROW / RPB)   // 768 blocks = 3/CU -> 3 waves/SIMD

#define LN2 0.69314718055994531f
#define INV_LN2 1.44269504088896341f

typedef _Float16 f16x8 __attribute__((ext_vector_type(8)));
typedef float f32x4 __attribute__((ext_vector_type(4)));

__device__ inline float waveReduceSum(float v) {
#pragma unroll
  for (int off = 32; off > 0; off >>= 1) v += __shfl_xor(v, off, 64);
  return v;
}

// Per-row squared norms + fp16 conversion. x is pre-scaled by 20/ln2 so the
// MFMA directly yields the base-2 LSE cross term (20*x.y)/ln2. 8 rows / block.
__global__ __launch_bounds__(256) void prep_kernel(const float* __restrict__ x,
                                                   const float* __restrict__ y,
                                                   _Float16* __restrict__ xh,
                                                   _Float16* __restrict__ yh,
                                                   float* __restrict__ x2,
                                                   float* __restrict__ y2,
                                                   float* __restrict__ vb) {
  int t = threadIdx.x;
  int row = blockIdx.x * 8 + (t >> 5);     // 0..24575
  int k = t & 31;
  if (row < NROW) {
    float val = x[(size_t)row * 32 + k];
    float sq = val * val;
#pragma unroll
    for (int off = 16; off > 0; off >>= 1) sq += __shfl_xor(sq, off, 64);
    xh[(size_t)row * 32 + k] = (_Float16)(20.0f * INV_LN2 * val);
    if (k == 0) x2[row] = sq;
  } else {
    int r = row - NROW;
    float val = y[(size_t)r * 32 + k];
    float sq = val * val;
#pragma unroll
    for (int off = 16; off > 0; off >>= 1) sq += __shfl_xor(sq, off, 64);
    yh[(size_t)r * 32 + k] = (_Float16)val;
    // vb = 10*(v - y2)/ln2 with v=0 (base-2 bias domain)
    if (k == 0) { y2[r] = sq; vb[r] = -10.0f * INV_LN2 * sq; }
  }
}

// One Sinkhorn half-step, C recomputed on the fly via fp16 MFMA, LSE in base 2:
//   arg2_ij = bias2_j + (20/ln2)*x_i.y_j   (bias folded into MFMA C operand)
//   pot_new_i = 0.1*log_mu + nrm_i - 0.1*ln2*LSE2_j(arg2)
// PASS 0: rows=x (u update, err tracked).  PASS 1: rows=y (v update, done flag).
// Block: 16 rows (one row-tile); 4 waves each own 768 cols; LDS merge at end.
template <int PASS>
__global__ __launch_bounds__(256) void lse_kernel(const _Float16* __restrict__ A16,
                                                  const _Float16* __restrict__ B16,
                                                  const float* __restrict__ biasIn,
                                                  const float* __restrict__ nrm,
                                                  float* __restrict__ pot,
                                                  float* __restrict__ biasOut,
                                                  float* __restrict__ errpart,
                                                  int* __restrict__ done_arr,
                                                  int it, float lmn) {
  int tid = threadIdx.x;
  if (done_arr[it]) {
    if (PASS == 1 && blockIdx.x == 0 && tid == 0) done_arr[it + 1] = 1;
    return;
  }
  int gr0 = blockIdx.x * RPB;        // flattened row base (b*P + i0), no batch straddle
  int b = gr0 / P;
  int lane = tid & 63;
  int w = tid >> 6;
  int rsel = lane & 15;
  int ksel = (lane >> 4) * 8;
  f16x8 afr = *(const f16x8*)(A16 + ((size_t)(gr0 + rsel)) * 32 + ksel);
  const size_t bb0 = (size_t)b * P;
  int j0 = w * 768;
  const _Float16* Bp = B16 + (bb0 + j0 + rsel) * 32 + ksel;
  const float* biasp = biasIn + bb0 + j0 + rsel;
  float m[4], s[4];
#pragma unroll
  for (int r = 0; r < 4; ++r) { m[r] = -1e30f; s[r] = 0.f; }
#pragma unroll 3
  for (int c = 0; c < 12; ++c) {     // 12 chunks x 64 cols
    f16x8 bfr[4];
    float bb[4];
#pragma unroll
    for (int t4 = 0; t4 < 4; ++t4) {
      int off = c * 64 + t4 * 16;
      bfr[t4] = *(const f16x8*)(Bp + (size_t)off * 32);
      bb[t4] = biasp[off];
    }
    f32x4 acc[4];
#pragma unroll
    for (int t4 = 0; t4 < 4; ++t4) {
      f32x4 ci = {bb[t4], bb[t4], bb[t4], bb[t4]};
      acc[t4] = __builtin_amdgcn_mfma_f32_16x16x32_f16(afr, bfr[t4], ci, 0, 0, 0);
    }
    // online LSE (base 2), chunk-max first: 1.25 exp / element
#pragma unroll
    for (int r = 0; r < 4; ++r) {
      float a0 = acc[0][r], a1 = acc[1][r], a2 = acc[2][r], a3 = acc[3][r];
      float cm = fmaxf(fmaxf(a0, a1), fmaxf(a2, a3));
      float nm = fmaxf(m[r], cm);
      float e = exp2f(a0 - nm) + exp2f(a1 - nm) + exp2f(a2 - nm) + exp2f(a3 - nm);
      s[r] = s[r] * exp2f(m[r] - nm) + e;
      m[r] = nm;
    }
  }
  // butterfly merge across the 16-lane col groups (row stays fixed: xor bits 0-3)
#pragma unroll
  for (int r = 0; r < 4; ++r) {
#pragma unroll
    for (int off = 1; off < 16; off <<= 1) {
      float om = __shfl_xor(m[r], off, 64);
      float os = __shfl_xor(s[r], off, 64);
      float nm = fmaxf(m[r], om);
      s[r] = s[r] * exp2f(m[r] - nm) + os * exp2f(om - nm);
      m[r] = nm;
    }
  }
  __shared__ float lm[4][RPB], ls[4][RPB];
  if (rsel == 0) {
    int g = lane >> 4;
#pragma unroll
    for (int r = 0; r < 4; ++r) {
      lm[w][g * 4 + r] = m[r];
      ls[w][g * 4 + r] = s[r];
    }
  }
  __syncthreads();
  float e = 0.f;
  if (tid < RPB) {
    float M = lm[0][tid], S = ls[0][tid];
#pragma unroll
    for (int w2 = 1; w2 < 4; ++w2) {
      float om = lm[w2][tid], os = ls[w2][tid];
      float nm = fmaxf(M, om);
      S = S * exp2f(M - nm) + os * exp2f(om - nm);
      M = nm;
    }
    float L2v = M + __log2f(S);        // base-2 LSE
    int gi = gr0 + tid;
    float nv = 0.1f * lmn + nrm[gi] - 0.1f * LN2 * L2v;
    if (PASS == 0) e = fabsf(nv - pot[gi]);
    pot[gi] = nv;
    biasOut[gi] = 10.0f * INV_LN2 * (nv - nrm[gi]);
  }
  if (PASS == 0) {
    if (tid < 64) {
      e = waveReduceSum(e);
      if (tid == 0) errpart[blockIdx.x] = e;
    }
  } else if (blockIdx.x == 0) {        // errpart complete (prev kernel in stream)
    __shared__ float rr[4];
    float ts = 0.f;
    for (int q = tid; q < LSE_GRID; q += 256) ts += errpart[q];
    ts = waveReduceSum(ts);
    if ((tid & 63) == 0) rr[tid >> 6] = ts;
    __syncthreads();
    if (tid == 0)
      done_arr[it + 1] = ((rr[0] + rr[1] + rr[2] + rr[3]) * 0.25f < 0.1f) ? 1 : 0;
  }
}

// Single fused epilogue: exact fp32 C, pi = exp((u+v-C)*10), cost partials.
// 64x64 tile, LDS-staged x/y, 4x4 accumulators per thread. No C read-back ever.
__global__ __launch_bounds__(256) void final_kernel(const float* __restrict__ x,
                                                    const float* __restrict__ y,
                                                    const float* __restrict__ x2,
                                                    const float* __restrict__ y2,
                                                    const float* __restrict__ u,
                                                    const float* __restrict__ v,
                                                    float* __restrict__ C,
                                                    float* __restrict__ pi,
                                                    float* __restrict__ costpart) {
  __shared__ float xs[64][33];
  __shared__ float ys[64][33];
  int t = threadIdx.x;
  int b = blockIdx.z;
  int i0 = blockIdx.x * 64;
  int j0 = blockIdx.y * 64;
  const float4* xg = (const float4*)(x + ((size_t)b * P + i0) * 32);
  const float4* yg = (const float4*)(y + ((size_t)b * P + j0) * 32);
#pragma unroll
  for (int k = 0; k < 2; ++k) {
    int f4 = t + k * 256;
    int row = f4 >> 3;
    int col = (f4 & 7) << 2;
    float4 xv = xg[f4];
    xs[row][col] = xv.x; xs[row][col + 1] = xv.y; xs[row][col + 2] = xv.z; xs[row][col + 3] = xv.w;
    float4 yv = yg[f4];
    ys[row][col] = yv.x; ys[row][col + 1] = yv.y; ys[row][col + 2] = yv.z; ys[row][col + 3] = yv.w;
  }
  __syncthreads();
  int ti = t >> 4, tj = t & 15;
  int ib = ti * 4, jb = tj * 4;
  float acc[4][4];
#pragma unroll
  for (int a = 0; a < 4; ++a)
#pragma unroll
    for (int bb = 0; bb < 4; ++bb) acc[a][bb] = 0.f;
#pragma unroll 8
  for (int k = 0; k < 32; ++k) {
    float xa[4], yb[4];
#pragma unroll
    for (int a = 0; a < 4; ++a) xa[a] = xs[ib + a][k];
#pragma unroll
    for (int bb = 0; bb < 4; ++bb) yb[bb] = ys[jb + bb][k];
#pragma unroll
    for (int a = 0; a < 4; ++a)
#pragma unroll
      for (int bb = 0; bb < 4; ++bb) acc[a][bb] = fmaf(xa[a], yb[bb], acc[a][bb]);
  }
  float y2r[4], vr[4];
#pragma unroll
  for (int bb = 0; bb < 4; ++bb) {
    y2r[bb] = y2[b * P + j0 + jb + bb];
    vr[bb] = v[b * P + j0 + jb + bb];
  }
  float costacc = 0.f;
#pragma unroll
  for (int a = 0; a < 4; ++a) {
    int gi = b * P + i0 + ib + a;
    float x2r = x2[gi];
    float ur = u[gi];
    float4 co, po;
    co.x = x2r + y2r[0] - 2.f * acc[a][0];
    co.y = x2r + y2r[1] - 2.f * acc[a][1];
    co.z = x2r + y2r[2] - 2.f * acc[a][2];
    co.w = x2r + y2r[3] - 2.f * acc[a][3];
    po.x = __expf((ur + vr[0] - co.x) * 10.f);
    po.y = __expf((ur + vr[1] - co.y) * 10.f);
    po.z = __expf((ur + vr[2] - co.z) * 10.f);
    po.w = __expf((ur + vr[3] - co.w) * 10.f);
    costacc += po.x * co.x + po.y * co.y + po.z * co.z + po.w * co.w;
    float* crow = C + (size_t)gi * P + j0;
    ((float4*)crow)[tj] = co;
    float* prow = pi + (size_t)gi * P + j0;
    ((float4*)prow)[tj] = po;
  }
  costacc = waveReduceSum(costacc);
  __shared__ float red[4];
  if ((t & 63) == 0) red[t >> 6] = costacc;
  __syncthreads();
  if (t == 0)
    costpart[((size_t)b * 48 + blockIdx.y) * 48 + blockIdx.x] =
        red[0] + red[1] + red[2] + red[3];
}

__global__ __launch_bounds__(256) void cost_kernel(const float* __restrict__ costpart,
                                                   float* __restrict__ cost) {
  __shared__ float red[4];
  int t = threadIdx.x;
  for (int b = 0; b < BATCH; ++b) {
    float loc = 0.f;
    for (int idx = t; idx < 2304; idx += 256) loc += costpart[b * 2304 + idx];
    loc = waveReduceSum(loc);
    if ((t & 63) == 0) red[t >> 6] = loc;
    __syncthreads();
    if (t == 0) cost[b] = red[0] + red[1] + red[2] + red[3];
    __syncthreads();
  }
}

extern "C" void kernel_launch(void* const* d_in, const int* in_sizes, int n_in,
                              void* d_out, int out_size, void* d_ws, size_t ws_size,
                              hipStream_t stream) {
  (void)in_sizes; (void)n_in; (void)out_size; (void)ws_size;
  const float* x = (const float*)d_in[0];
  const float* y = (const float*)d_in[1];
  float* out = (float*)d_out;
  float* cost = out;                          // [4]
  float* pi = out + 4;                        // [4*3072*3072]
  float* C = pi + (size_t)BATCH * P * P;      // [4*3072*3072]

  float* u = (float*)d_ws;                    // 12288
  int* done_arr = (int*)(u + NROW);           // 64 ints
  float* v = (float*)(done_arr + 64);         // 12288
  float* ub = v + NROW;                       // 12288  (10/ln2*(u - x2))
  float* vb = ub + NROW;                      // 12288  (10/ln2*(v - y2))
  float* x2 = vb + NROW;                      // 12288
  float* y2 = x2 + NROW;                      // 12288
  float* errpart = y2 + NROW;                 // 768
  float* costpart = errpart + LSE_GRID;       // 9216   (~340 KB total ws)

  // fp16 scratch lives in the C output region (only written at the end; 16B-aligned)
  _Float16* xh = (_Float16*)C;                // [12288][32] = 20/ln2 * x
  _Float16* yh = xh + (size_t)NROW * 32;      // [12288][32] = y

  // zero u and done_arr[0..] (harness poisons ws each call)
  hipMemsetAsync(d_ws, 0, (size_t)NROW * sizeof(float) + 64 * sizeof(int), stream);

  float lmn = logf(1.0f / 3072.0f + 1e-8f);   // log_mu == log_nu

  prep_kernel<<<3072, 256, 0, stream>>>(x, y, xh, yh, x2, y2, vb);

  for (int it = 0; it < MAXIT; ++it) {
    lse_kernel<0><<<LSE_GRID, 256, 0, stream>>>(xh, yh, vb, x2, u, ub, errpart,
                                                done_arr, it, lmn);
    lse_kernel<1><<<LSE_GRID, 256, 0, stream>>>(yh, xh, ub, y2, v, vb, errpart,
                                                done_arr, it, lmn);
  }

  final_kernel<<<dim3(48, 48, 4), 256, 0, stream>>>(x, y, x2, y2, u, v, C, pi, costpart);
  cost_kernel<<<1, 256, 0, stream>>>(costpart, cost);
}

// Round 3
// 1702.325 us; speedup vs baseline: 1.3684x; 1.3684x over previous
//
#include <hip/hip_runtime.h>
#include <math.h>

#define BATCH 4
#define P 3072
#define NROW (BATCH * P)        // 12288
#define NTILE (NROW / 16)       // 768 row-tiles (16 rows each); none straddle a batch
#define TPB (P / 16)            // 192 tiles per batch
#define MAXIT 50
#define LSE_GRID NTILE          // 768 blocks = 3/CU

#define LN2 0.69314718055994531f
#define INV_LN2 1.44269504088896341f

typedef _Float16 f16x8 __attribute__((ext_vector_type(8)));
typedef float f32x4 __attribute__((ext_vector_type(4)));

__device__ inline float waveReduceSum(float v) {
#pragma unroll
  for (int off = 32; off > 0; off >>= 1) v += __shfl_xor(v, off, 64);
  return v;
}
// guaranteed single-instruction exp2 / log2 (library exp2f has a denorm-fixup path)
__device__ inline float fexp2(float x) { return __builtin_amdgcn_exp2f(x); }
__device__ inline float flog2(float x) { return __builtin_amdgcn_logf(x); }

// Pack x/y into MFMA-fragment-major fp16 tiles:
//   frag[tile][g][r][8]  (g = k-octet 0..3, r = row-in-tile 0..15, 1 KB per tile)
// so lane l of a wave loads its A/B fragment for tile T at byte T*1024 + l*16 —
// a single fully-coalesced contiguous 1 KB wave-load (the R2 kernel's strided
// fragment loads cost 4x L1 bandwidth). x is pre-scaled by 20/ln2 so MFMA yields
// the base-2 LSE cross term directly. Also emits row squared-norms.
__global__ __launch_bounds__(256) void prep_kernel(const float* __restrict__ x,
                                                   const float* __restrict__ y,
                                                   _Float16* __restrict__ xh,
                                                   _Float16* __restrict__ yh,
                                                   float* __restrict__ x2,
                                                   float* __restrict__ y2,
                                                   float* __restrict__ vb) {
  int t = threadIdx.x;
  int lane = t & 63;
  int g = lane >> 4, r = lane & 15;
  int tileG = blockIdx.x * 4 + (t >> 6);     // 0..1535 (x tiles then y tiles)
  int isY = tileG >= NTILE;
  int tile = isY ? (tileG - NTILE) : tileG;
  const float* src = isY ? y : x;
  int row = tile * 16 + r;
  const float* p = src + (size_t)row * 32 + g * 8;
  float4 v0 = *(const float4*)p;
  float4 v1 = *(const float4*)(p + 4);
  float sq = v0.x * v0.x + v0.y * v0.y + v0.z * v0.z + v0.w * v0.w +
             v1.x * v1.x + v1.y * v1.y + v1.z * v1.z + v1.w * v1.w;
  sq += __shfl_xor(sq, 16, 64);
  sq += __shfl_xor(sq, 32, 64);                // lanes with same r now hold row sum
  float scale = isY ? 1.0f : 20.0f * INV_LN2;
  f16x8 h;
  h[0] = (_Float16)(scale * v0.x); h[1] = (_Float16)(scale * v0.y);
  h[2] = (_Float16)(scale * v0.z); h[3] = (_Float16)(scale * v0.w);
  h[4] = (_Float16)(scale * v1.x); h[5] = (_Float16)(scale * v1.y);
  h[6] = (_Float16)(scale * v1.z); h[7] = (_Float16)(scale * v1.w);
  _Float16* dst = (isY ? yh : xh) + (size_t)tile * 512 + lane * 8;
  *(f16x8*)dst = h;                            // wave writes contiguous 1 KB
  if (lane < 16) {
    if (isY) { y2[row] = sq; vb[row] = -10.0f * INV_LN2 * sq; }  // v=0 bias
    else     { x2[row] = sq; }
  }
}

// One Sinkhorn half-step, C recomputed on the fly via fp16 MFMA, LSE in base 2:
//   arg2_ij = bias2_j + (20/ln2)*x_i.y_j   (bias folded into MFMA C operand)
//   pot_new_i = 0.1*log_mu + nrm_i - 0.1*ln2*LSE2_j(arg2)
// PASS 0: rows=x (u update, err tracked).  PASS 1: rows=y (v update, done flag).
// Block: one 16-row tile; 4 waves each own 768 cols (48 col-tiles); LDS merge.
template <int PASS>
__global__ __launch_bounds__(256) void lse_kernel(const _Float16* __restrict__ A16,
                                                  const _Float16* __restrict__ B16,
                                                  const float* __restrict__ biasIn,
                                                  const float* __restrict__ nrm,
                                                  float* __restrict__ pot,
                                                  float* __restrict__ biasOut,
                                                  float* __restrict__ errpart,
                                                  int* __restrict__ done_arr,
                                                  int it, float lmn) {
  int tid = threadIdx.x;
  if (done_arr[it]) {
    if (PASS == 1 && blockIdx.x == 0 && tid == 0) done_arr[it + 1] = 1;
    return;
  }
  int lane = tid & 63;
  int w = tid >> 6;
  int rsel = lane & 15;
  int b = blockIdx.x / TPB;
  // A fragment: one coalesced 1 KB wave-load
  f16x8 afr = *(const f16x8*)(A16 + (size_t)blockIdx.x * 512 + lane * 8);
  int jt0 = b * TPB + w * 48;                  // this wave's first col-tile
  const _Float16* Bp = B16 + (size_t)jt0 * 512 + lane * 8;
  const float* biasp = biasIn + b * P + w * 768 + rsel;
  float m[4], s[4];
#pragma unroll
  for (int r = 0; r < 4; ++r) { m[r] = -1e30f; s[r] = 0.f; }
#pragma unroll 3
  for (int c = 0; c < 12; ++c) {               // 12 chunks x 4 col-tiles
    f16x8 bfr[4];
    float bb[4];
#pragma unroll
    for (int t4 = 0; t4 < 4; ++t4) {
      bfr[t4] = *(const f16x8*)(Bp + ((size_t)(c * 4 + t4) << 9));  // coalesced 1 KB
      bb[t4] = biasp[(c * 4 + t4) * 16];
    }
    f32x4 acc[4];
#pragma unroll
    for (int t4 = 0; t4 < 4; ++t4) {
      f32x4 ci = {bb[t4], bb[t4], bb[t4], bb[t4]};
      acc[t4] = __builtin_amdgcn_mfma_f32_16x16x32_f16(afr, bfr[t4], ci, 0, 0, 0);
    }
    // online LSE (base 2), chunk-max first: 1.25 exp2 / element
#pragma unroll
    for (int r = 0; r < 4; ++r) {
      float a0 = acc[0][r], a1 = acc[1][r], a2 = acc[2][r], a3 = acc[3][r];
      float cm = fmaxf(fmaxf(a0, a1), fmaxf(a2, a3));
      float nm = fmaxf(m[r], cm);
      float e = fexp2(a0 - nm) + fexp2(a1 - nm) + fexp2(a2 - nm) + fexp2(a3 - nm);
      s[r] = s[r] * fexp2(m[r] - nm) + e;
      m[r] = nm;
    }
  }
  // butterfly merge across the 16-lane col groups (row stays fixed: xor bits 0-3)
#pragma unroll
  for (int r = 0; r < 4; ++r) {
#pragma unroll
    for (int off = 1; off < 16; off <<= 1) {
      float om = __shfl_xor(m[r], off, 64);
      float os = __shfl_xor(s[r], off, 64);
      float nm = fmaxf(m[r], om);
      s[r] = s[r] * fexp2(m[r] - nm) + os * fexp2(om - nm);
      m[r] = nm;
    }
  }
  __shared__ float lm[4][16], ls[4][16];
  if (rsel == 0) {
    int g = lane >> 4;
#pragma unroll
    for (int r = 0; r < 4; ++r) {
      lm[w][g * 4 + r] = m[r];
      ls[w][g * 4 + r] = s[r];
    }
  }
  __syncthreads();
  float e = 0.f;
  if (tid < 16) {
    float M = lm[0][tid], S = ls[0][tid];
#pragma unroll
    for (int w2 = 1; w2 < 4; ++w2) {
      float om = lm[w2][tid], os = ls[w2][tid];
      float nm = fmaxf(M, om);
      S = S * fexp2(M - nm) + os * fexp2(om - nm);
      M = nm;
    }
    float L2v = M + flog2(S);                  // base-2 LSE
    int gi = blockIdx.x * 16 + tid;
    float nv = 0.1f * lmn + nrm[gi] - 0.1f * LN2 * L2v;
    if (PASS == 0) e = fabsf(nv - pot[gi]);
    pot[gi] = nv;
    biasOut[gi] = 10.0f * INV_LN2 * (nv - nrm[gi]);
  }
  if (PASS == 0) {
    if (tid < 64) {
      e = waveReduceSum(e);
      if (tid == 0) errpart[blockIdx.x] = e;
    }
  } else if (blockIdx.x == 0) {                // errpart complete (prev kernel)
    __shared__ float rr[4];
    float ts = 0.f;
    for (int q = tid; q < LSE_GRID; q += 256) ts += errpart[q];
    ts = waveReduceSum(ts);
    if ((tid & 63) == 0) rr[tid >> 6] = ts;
    __syncthreads();
    if (tid == 0)
      done_arr[it + 1] = ((rr[0] + rr[1] + rr[2] + rr[3]) * 0.25f < 0.1f) ? 1 : 0;
  }
}

// Single fused epilogue: exact fp32 C, pi = exp((u+v-C)*10), cost partials.
// 64x64 tile, LDS-staged x/y, 4x4 accumulators per thread. No C read-back ever.
__global__ __launch_bounds__(256) void final_kernel(const float* __restrict__ x,
                                                    const float* __restrict__ y,
                                                    const float* __restrict__ x2,
                                                    const float* __restrict__ y2,
                                                    const float* __restrict__ u,
                                                    const float* __restrict__ v,
                                                    float* __restrict__ C,
                                                    float* __restrict__ pi,
                                                    float* __restrict__ costpart) {
  __shared__ float xs[64][33];
  __shared__ float ys[64][33];
  int t = threadIdx.x;
  int b = blockIdx.z;
  int i0 = blockIdx.x * 64;
  int j0 = blockIdx.y * 64;
  const float4* xg = (const float4*)(x + ((size_t)b * P + i0) * 32);
  const float4* yg = (const float4*)(y + ((size_t)b * P + j0) * 32);
#pragma unroll
  for (int k = 0; k < 2; ++k) {
    int f4 = t + k * 256;
    int row = f4 >> 3;
    int col = (f4 & 7) << 2;
    float4 xv = xg[f4];
    xs[row][col] = xv.x; xs[row][col + 1] = xv.y; xs[row][col + 2] = xv.z; xs[row][col + 3] = xv.w;
    float4 yv = yg[f4];
    ys[row][col] = yv.x; ys[row][col + 1] = yv.y; ys[row][col + 2] = yv.z; ys[row][col + 3] = yv.w;
  }
  __syncthreads();
  int ti = t >> 4, tj = t & 15;
  int ib = ti * 4, jb = tj * 4;
  float acc[4][4];
#pragma unroll
  for (int a = 0; a < 4; ++a)
#pragma unroll
    for (int bb = 0; bb < 4; ++bb) acc[a][bb] = 0.f;
#pragma unroll 8
  for (int k = 0; k < 32; ++k) {
    float xa[4], yb[4];
#pragma unroll
    for (int a = 0; a < 4; ++a) xa[a] = xs[ib + a][k];
#pragma unroll
    for (int bb = 0; bb < 4; ++bb) yb[bb] = ys[jb + bb][k];
#pragma unroll
    for (int a = 0; a < 4; ++a)
#pragma unroll
      for (int bb = 0; bb < 4; ++bb) acc[a][bb] = fmaf(xa[a], yb[bb], acc[a][bb]);
  }
  float y2r[4], vr[4];
#pragma unroll
  for (int bb = 0; bb < 4; ++bb) {
    y2r[bb] = y2[b * P + j0 + jb + bb];
    vr[bb] = v[b * P + j0 + jb + bb];
  }
  float costacc = 0.f;
#pragma unroll
  for (int a = 0; a < 4; ++a) {
    int gi = b * P + i0 + ib + a;
    float x2r = x2[gi];
    float ur = u[gi];
    float4 co, po;
    co.x = x2r + y2r[0] - 2.f * acc[a][0];
    co.y = x2r + y2r[1] - 2.f * acc[a][1];
    co.z = x2r + y2r[2] - 2.f * acc[a][2];
    co.w = x2r + y2r[3] - 2.f * acc[a][3];
    po.x = __expf((ur + vr[0] - co.x) * 10.f);
    po.y = __expf((ur + vr[1] - co.y) * 10.f);
    po.z = __expf((ur + vr[2] - co.z) * 10.f);
    po.w = __expf((ur + vr[3] - co.w) * 10.f);
    costacc += po.x * co.x + po.y * co.y + po.z * co.z + po.w * co.w;
    float* crow = C + (size_t)gi * P + j0;
    ((float4*)crow)[tj] = co;
    float* prow = pi + (size_t)gi * P + j0;
    ((float4*)prow)[tj] = po;
  }
  costacc = waveReduceSum(costacc);
  __shared__ float red[4];
  if ((t & 63) == 0) red[t >> 6] = costacc;
  __syncthreads();
  if (t == 0)
    costpart[((size_t)b * 48 + blockIdx.y) * 48 + blockIdx.x] =
        red[0] + red[1] + red[2] + red[3];
}

__global__ __launch_bounds__(256) void cost_kernel(const float* __restrict__ costpart,
                                                   float* __restrict__ cost) {
  __shared__ float red[4];
  int t = threadIdx.x;
  for (int b = 0; b < BATCH; ++b) {
    float loc = 0.f;
    for (int idx = t; idx < 2304; idx += 256) loc += costpart[b * 2304 + idx];
    loc = waveReduceSum(loc);
    if ((t & 63) == 0) red[t >> 6] = loc;
    __syncthreads();
    if (t == 0) cost[b] = red[0] + red[1] + red[2] + red[3];
    __syncthreads();
  }
}

extern "C" void kernel_launch(void* const* d_in, const int* in_sizes, int n_in,
                              void* d_out, int out_size, void* d_ws, size_t ws_size,
                              hipStream_t stream) {
  (void)in_sizes; (void)n_in; (void)out_size; (void)ws_size;
  const float* x = (const float*)d_in[0];
  const float* y = (const float*)d_in[1];
  float* out = (float*)d_out;
  float* cost = out;                          // [4]
  float* pi = out + 4;                        // [4*3072*3072]
  float* C = pi + (size_t)BATCH * P * P;      // [4*3072*3072]

  float* u = (float*)d_ws;                    // 12288
  int* done_arr = (int*)(u + NROW);           // 64 ints
  float* v = (float*)(done_arr + 64);         // 12288
  float* ub = v + NROW;                       // 12288  (10/ln2*(u - x2))
  float* vb = ub + NROW;                      // 12288  (10/ln2*(v - y2))
  float* x2 = vb + NROW;                      // 12288
  float* y2 = x2 + NROW;                      // 12288
  float* errpart = y2 + NROW;                 // 768
  float* costpart = errpart + LSE_GRID;       // 9216   (~340 KB total ws)

  // fp16 fragment-packed scratch lives in the C output region (written last;
  // base is 16 B aligned: (4 + 4*3072*3072) floats from out)
  _Float16* xh = (_Float16*)C;                // [768 tiles][1 KB] = 20/ln2 * x
  _Float16* yh = xh + (size_t)NROW * 32;      // [768 tiles][1 KB] = y

  // zero u and done_arr[0..] (harness poisons ws each call)
  hipMemsetAsync(d_ws, 0, (size_t)NROW * sizeof(float) + 64 * sizeof(int), stream);

  float lmn = logf(1.0f / 3072.0f + 1e-8f);   // log_mu == log_nu

  prep_kernel<<<384, 256, 0, stream>>>(x, y, xh, yh, x2, y2, vb);

  for (int it = 0; it < MAXIT; ++it) {
    lse_kernel<0><<<LSE_GRID, 256, 0, stream>>>(xh, yh, vb, x2, u, ub, errpart,
                                                done_arr, it, lmn);
    lse_kernel<1><<<LSE_GRID, 256, 0, stream>>>(yh, xh, ub, y2, v, vb, errpart,
                                                done_arr, it, lmn);
  }

  final_kernel<<<dim3(48, 48, 4), 256, 0, stream>>>(x, y, x2, y2, u, v, C, pi, costpart);
  cost_kernel<<<1, 256, 0, stream>>>(costpart, cost);
}